// Round 8
// baseline (533.772 us; speedup 1.0000x reference)
//
#include <hip/hip_runtime.h>

#define NHEADS 16
#define DEMBED 1024
#define DCROSS 768
#define DHEAD  64
#define BATCH  4
#define SLEN   2048
#define MROWS  (BATCH * SLEN)   // 8192

using bf16   = __bf16;
using bf16x8 = __attribute__((ext_vector_type(8))) __bf16;
using bf16x4 = __attribute__((ext_vector_type(4))) __bf16;
using f32x4  = __attribute__((ext_vector_type(4))) float;

__device__ __forceinline__ f32x4 mfma_bf16(bf16x8 a, bf16x8 b, f32x4 c) {
    return __builtin_amdgcn_mfma_f32_16x16x32_bf16(a, b, c, 0, 0, 0);
}

// async global->LDS, 16B per lane; lds dest = wave-uniform base + lane*16
__device__ __forceinline__ void gl2lds16(const void* g, void* l) {
    __builtin_amdgcn_global_load_lds(
        (const __attribute__((address_space(1))) void*)g,
        (__attribute__((address_space(3))) void*)l, 16, 0, 0);
}

// ---------------------------------------------------------------- prep (one kernel)
struct PrepArgs {
    const float* wsrc[4]; bf16* wdst[4]; int wK[4];
    const float *x, *y; bf16 *xb, *yb;
};
#define NTRB 4096
__global__ void prep_all(PrepArgs a) {
    const int bid = blockIdx.x;
    const int tid = threadIdx.x;
    if (bid < NTRB) {
        __shared__ float tile[32][33];
        const int which = bid >> 10, rem = bid & 1023;
        const int K = a.wK[which], N = DEMBED;
        const int n0 = (rem & 31) * 32, k0 = (rem >> 5) * 32;
        if (k0 >= K) return;
        const float* W = a.wsrc[which];
        bf16* Wt = a.wdst[which];
        const int tx = tid & 31, ty = tid >> 5;
#pragma unroll
        for (int i = 0; i < 32; i += 8)
            tile[ty + i][tx] = W[(size_t)(k0 + ty + i) * N + n0 + tx];
        __syncthreads();
#pragma unroll
        for (int i = 0; i < 32; i += 8)
            Wt[(size_t)(n0 + ty + i) * K + k0 + tx] = (bf16)tile[tx][ty + i];
    } else {
        const int n4x = MROWS * DEMBED / 4;
        const int n4y = MROWS * DCROSS / 4;
        int i = (bid - NTRB) * 256 + tid;
        const float* src; bf16* dst; int j;
        if (i < n4x) { src = a.x; dst = a.xb; j = i; }
        else { j = i - n4x; if (j >= n4y) return; src = a.y; dst = a.yb; }
        float4 v = ((const float4*)src)[j];
        bf16x4 o = { (bf16)v.x, (bf16)v.y, (bf16)v.z, (bf16)v.w };
        ((bf16x4*)dst)[j] = o;
    }
}

// ---------------------------------------------------------------- fused QKV GEMM
// 256x128 tile, 512 threads (8 waves, 4x2 of 64x64), BK=64. B staged once per
// 256 A-rows; 768 blocks = exactly 3/CU (48 KB LDS). 16B async staging,
// XOR-swizzled LDS.
// blocks: [0,256) Q = xb@Wqt^T (*qscale), [256,512) K = yb@Wkt^T,
// [512,768) V^T = Wvt@yb^T written per-head transposed.
struct QkvArgs {
    const bf16 *xb, *yb, *Wqt, *Wkt, *Wvt;
    const float *bq, *bk, *bv;
    bf16 *Qb, *Kb, *Vt;
    float qscale;
};
__global__ __launch_bounds__(512, 6) void gemm_qkv(QkvArgs a) {
    __shared__ bf16 As[256 * 64];   // 32 KB
    __shared__ bf16 Bs[128 * 64];   // 16 KB
    const int id = blockIdx.x;
    const int cls = id >> 8;   // 0=Q 1=K 2=V
    const bf16 *A, *Bt;
    const float* bias;
    int K, m0, n0;
    if (cls == 0) { int t = id;       m0 = (t >> 3) * 256; n0 = (t & 7) * 128;
                    A = a.xb;  Bt = a.Wqt; bias = a.bq; K = DEMBED; }
    else if (cls == 1) { int t = id - 256; m0 = (t >> 3) * 256; n0 = (t & 7) * 128;
                    A = a.yb;  Bt = a.Wkt; bias = a.bk; K = DCROSS; }
    else { int t = id - 512; m0 = (t >> 6) * 256; n0 = (t & 63) * 128;
                    A = a.Wvt; Bt = a.yb;  bias = a.bv; K = DCROSS; }

    const int tid  = threadIdx.x;
    const int wave = tid >> 6, lane = tid & 63;
    const int quad = lane >> 4, l15 = lane & 15;
    const int wr = wave >> 1, wc = wave & 1;

    // staging: call c covers rows c*64 + (tid>>3); phys chunk lane&7 holds
    // logical chunk (lane&7)^(row&7), row&7 == lane>>3.
    const int srow = tid >> 3;                         // 0..63 within a call
    const int scol = ((lane & 7) ^ (lane >> 3)) * 8;   // logical element col
    char* ldsA0 = (char*)As + wave * 1024;
    char* ldsB0 = (char*)Bs + wave * 1024;
    const bf16* gA0 = A + (size_t)(m0 + srow) * K + scol;
    const bf16* gB0 = Bt + (size_t)(n0 + srow) * K + scol;

    const int sw = l15 & 7;   // read-side swizzle (row & 7)

    f32x4 acc[4][4] = {};

    for (int kt = 0; kt < K; kt += 64) {
        __syncthreads();
#pragma unroll
        for (int c = 0; c < 4; c++)
            gl2lds16(gA0 + (size_t)c * 64 * K + kt, ldsA0 + c * 8192);
#pragma unroll
        for (int c = 0; c < 2; c++)
            gl2lds16(gB0 + (size_t)c * 64 * K + kt, ldsB0 + c * 8192);
        __syncthreads();

#pragma unroll
        for (int kg = 0; kg < 2; kg++) {
            bf16x8 af[4], bfr[4];
#pragma unroll
            for (int i = 0; i < 4; i++)
                af[i] = *(const bf16x8*)((const char*)As +
                         (wr * 64 + i * 16 + l15) * 128 + (((kg * 4 + quad) ^ sw) * 16));
#pragma unroll
            for (int i = 0; i < 4; i++)
                bfr[i] = *(const bf16x8*)((const char*)Bs +
                         (wc * 64 + i * 16 + l15) * 128 + (((kg * 4 + quad) ^ sw) * 16));
#pragma unroll
            for (int fr = 0; fr < 4; fr++)
#pragma unroll
                for (int fc = 0; fc < 4; fc++)
                    acc[fr][fc] = mfma_bf16(af[fr], bfr[fc], acc[fr][fc]);
        }
    }

    if (cls < 2) {
        bf16* Cout = (cls == 0) ? a.Qb : a.Kb;
        const float alpha = (cls == 0) ? a.qscale : 1.0f;
#pragma unroll
        for (int fr = 0; fr < 4; fr++) {
            int row = m0 + wr * 64 + fr * 16 + quad * 4;
#pragma unroll
            for (int fc = 0; fc < 4; fc++) {
                int col = n0 + wc * 64 + fc * 16 + l15;
                float bv = bias[col];
#pragma unroll
                for (int r = 0; r < 4; r++)
                    Cout[(size_t)(row + r) * DEMBED + col] =
                        (bf16)((acc[fr][fc][r] + bv) * alpha);
            }
        }
    } else {
        const int b = n0 >> 11;
        const size_t bbase = (size_t)b * DEMBED * SLEN;
#pragma unroll
        for (int fr = 0; fr < 4; fr++) {
            int row = m0 + wr * 64 + fr * 16 + quad * 4;   // embed index
#pragma unroll
            for (int fc = 0; fc < 4; fc++) {
                int col = n0 + wc * 64 + fc * 16 + l15;
                int s = col & (SLEN - 1);
#pragma unroll
                for (int r = 0; r < 4; r++)
                    a.Vt[bbase + (size_t)(row + r) * SLEN + s] =
                        (bf16)(acc[fr][fc][r] + bias[row + r]);
            }
        }
    }
}

// ---------------------------------------------------------------- O GEMM (BK=64)
__global__ __launch_bounds__(256, 3) void gemm_o(const bf16* __restrict__ A,
                                                 const bf16* __restrict__ Bt,
                                                 const float* __restrict__ bias,
                                                 float* __restrict__ Cout) {
    const int K = DEMBED, N = DEMBED;
    __shared__ bf16 As[128 * 64];
    __shared__ bf16 Bs[128 * 64];
    const int tid  = threadIdx.x;
    const int wave = tid >> 6, lane = tid & 63;
    const int quad = lane >> 4, l15 = lane & 15;
    const int m0 = blockIdx.x * 128, n0 = blockIdx.y * 128;
    const int wr = wave >> 1, wc = wave & 1;

    const int srow = wave * 8 + (lane >> 3);
    const int scol = ((lane & 7) ^ (lane >> 3)) * 8;
    char* ldsA0 = (char*)As + wave * 1024;
    char* ldsB0 = (char*)Bs + wave * 1024;
    const bf16* gA0 = A + (size_t)(m0 + srow) * K + scol;
    const bf16* gB0 = Bt + (size_t)(n0 + srow) * K + scol;

    const int sw = l15 & 7;

    f32x4 acc[4][4] = {};

    for (int kt = 0; kt < K; kt += 64) {
        __syncthreads();
#pragma unroll
        for (int c = 0; c < 4; c++)
            gl2lds16(gA0 + (size_t)c * 32 * K + kt, ldsA0 + c * 4096);
#pragma unroll
        for (int c = 0; c < 4; c++)
            gl2lds16(gB0 + (size_t)c * 32 * K + kt, ldsB0 + c * 4096);
        __syncthreads();

#pragma unroll
        for (int kg = 0; kg < 2; kg++) {
            bf16x8 af[4], bfr[4];
#pragma unroll
            for (int i = 0; i < 4; i++)
                af[i] = *(const bf16x8*)((const char*)As +
                         (wr * 64 + i * 16 + l15) * 128 + (((kg * 4 + quad) ^ sw) * 16));
#pragma unroll
            for (int i = 0; i < 4; i++)
                bfr[i] = *(const bf16x8*)((const char*)Bs +
                         (wc * 64 + i * 16 + l15) * 128 + (((kg * 4 + quad) ^ sw) * 16));
#pragma unroll
            for (int fr = 0; fr < 4; fr++)
#pragma unroll
                for (int fc = 0; fc < 4; fc++)
                    acc[fr][fc] = mfma_bf16(af[fr], bfr[fc], acc[fr][fc]);
        }
    }

#pragma unroll
    for (int fr = 0; fr < 4; fr++) {
        int row = m0 + wr * 64 + fr * 16 + quad * 4;
#pragma unroll
        for (int fc = 0; fc < 4; fc++) {
            int col = n0 + wc * 64 + fc * 16 + l15;
            float bv = bias[col];
#pragma unroll
            for (int r = 0; r < 4; r++)
                Cout[(size_t)(row + r) * N + col] = acc[fr][fc][r] + bv;
        }
    }
}

// ---------------------------------------------------------------- attention
// Round-6 structure (LDS-staged K/V, 4 blocks/CU) + register-hoisted P reads
// (the dg-loop P reads were re-issued 4x; hoisting cuts ~12 KB/wave-tile of
// LDS traffic). grid (bh, qblk) keeps each head's K/V on one XCD's L2.
__global__ __launch_bounds__(256, 4) void attn(const bf16* __restrict__ Q,
                                               const bf16* __restrict__ K,
                                               const bf16* __restrict__ Vt,
                                               bf16* __restrict__ O) {
    __shared__ bf16 KsA[64 * 64];        // [key][d]   XOR-swizzled chunks
    __shared__ bf16 VsA[64 * 64];        // [d][key]   XOR-swizzled chunks
    __shared__ bf16 PsA[4 * 32 * 72];    // per-wave [q][key], pad 72

    const int tid  = threadIdx.x;
    const int wave = tid >> 6, lane = tid & 63;
    const int quad = lane >> 4, l15 = lane & 15;
    const int bh = blockIdx.x, b = bh >> 4, h = bh & 15;
    const size_t rowbase = (size_t)b * SLEN;
    const int qb = blockIdx.y * 128 + wave * 32;
    const int hc = h * DHEAD;

    bf16x8 qf[2][2];
#pragma unroll
    for (int rg = 0; rg < 2; rg++)
#pragma unroll
        for (int kg = 0; kg < 2; kg++)
            qf[rg][kg] = *(const bf16x8*)(Q + (rowbase + qb + rg * 16 + l15) * DEMBED
                                          + hc + kg * 32 + quad * 8);

    f32x4 o[2][4] = {};
    f32x4 lsv[2] = {};

    const bf16* Kbase = K + rowbase * DEMBED + hc;
    const bf16* Vbase = Vt + (size_t)bh * DHEAD * SLEN;

    const int xcol = (((tid & 7) ^ ((tid >> 3) & 7)) * 8);
    const bf16* gK = Kbase + (size_t)(tid >> 3) * DEMBED + xcol;
    const bf16* gV = Vbase + (size_t)(tid >> 3) * SLEN + xcol;
    char* ldsK = (char*)KsA + wave * 1024;
    char* ldsV = (char*)VsA + wave * 1024;
    bf16* Pw = PsA + wave * (32 * 72);

    for (int kb = 0; kb < SLEN; kb += 64) {
        __syncthreads();
        gl2lds16(gK + (size_t)kb * DEMBED, ldsK);
        gl2lds16(gK + (size_t)(kb + 32) * DEMBED, ldsK + 32 * 128);
        gl2lds16(gV + kb, ldsV);
        gl2lds16(gV + 32 * SLEN + kb, ldsV + 32 * 128);
        __syncthreads();

        f32x4 s[2][4] = {};
#pragma unroll
        for (int cg = 0; cg < 4; cg++)
#pragma unroll
            for (int kg = 0; kg < 2; kg++) {
                bf16x8 kf = *(const bf16x8*)((const char*)KsA +
                            (cg * 16 + l15) * 128 + (((kg * 4 + quad) ^ (l15 & 7)) * 16));
#pragma unroll
                for (int rg = 0; rg < 2; rg++)
                    s[rg][cg] = mfma_bf16(kf, qf[rg][kg], s[rg][cg]);
            }

#pragma unroll
        for (int rg = 0; rg < 2; rg++)
#pragma unroll
            for (int cg = 0; cg < 4; cg++) {
                f32x4 p;
                p[0] = __builtin_amdgcn_exp2f(s[rg][cg][0]);
                p[1] = __builtin_amdgcn_exp2f(s[rg][cg][1]);
                p[2] = __builtin_amdgcn_exp2f(s[rg][cg][2]);
                p[3] = __builtin_amdgcn_exp2f(s[rg][cg][3]);
                lsv[rg] += p;
                bf16x4 pb = { (bf16)p[0], (bf16)p[1], (bf16)p[2], (bf16)p[3] };
                *(bf16x4*)(Pw + (rg * 16 + l15) * 72 + cg * 16 + quad * 4) = pb;
            }

        // hoisted P fragment reads (wave-private LDS; in-wave lgkmcnt ordering)
        bf16x8 ap[2][2];
#pragma unroll
        for (int rg = 0; rg < 2; rg++)
#pragma unroll
            for (int kg = 0; kg < 2; kg++)
                ap[rg][kg] = *(const bf16x8*)(Pw + (rg * 16 + l15) * 72 + kg * 32 + quad * 8);

#pragma unroll
        for (int dg = 0; dg < 4; dg++)
#pragma unroll
            for (int kg = 0; kg < 2; kg++) {
                bf16x8 vf = *(const bf16x8*)((const char*)VsA +
                            (dg * 16 + l15) * 128 + (((kg * 4 + quad) ^ (l15 & 7)) * 16));
#pragma unroll
                for (int rg = 0; rg < 2; rg++)
                    o[rg][dg] = mfma_bf16(ap[rg][kg], vf, o[rg][dg]);
            }
    }

    float inv[2];
#pragma unroll
    for (int rg = 0; rg < 2; rg++) {
        float rs = lsv[rg][0] + lsv[rg][1] + lsv[rg][2] + lsv[rg][3];
        rs += __shfl_xor(rs, 16);
        rs += __shfl_xor(rs, 32);
        inv[rg] = 1.0f / rs;
    }
#pragma unroll
    for (int rg = 0; rg < 2; rg++)
#pragma unroll
        for (int r = 0; r < 4; r++) {
            float iv = __shfl(inv[rg], quad * 4 + r);
#pragma unroll
            for (int dg = 0; dg < 4; dg++)
                O[(rowbase + qb + rg * 16 + quad * 4 + r) * DEMBED + hc + dg * 16 + l15] =
                    (bf16)(o[rg][dg][r] * iv);
        }
}

// ---------------------------------------------------------------- launch
extern "C" void kernel_launch(void* const* d_in, const int* in_sizes, int n_in,
                              void* d_out, int out_size, void* d_ws, size_t ws_size,
                              hipStream_t stream) {
    const float* x  = (const float*)d_in[0];
    const float* y  = (const float*)d_in[1];
    const float* Wq = (const float*)d_in[2];
    const float* bq = (const float*)d_in[3];
    const float* Wk = (const float*)d_in[4];
    const float* bk = (const float*)d_in[5];
    const float* Wv = (const float*)d_in[6];
    const float* bv = (const float*)d_in[7];
    const float* Wo = (const float*)d_in[8];
    const float* bo = (const float*)d_in[9];
    float* out = (float*)d_out;

    char* ws = (char*)d_ws;
    size_t off = 0;
    auto alloc = [&](size_t bytes) {
        void* p = ws + off;
        off += (bytes + 255) & ~(size_t)255;
        return p;
    };
    bf16* xb  = (bf16*)alloc((size_t)MROWS * DEMBED * 2);
    bf16* yb  = (bf16*)alloc((size_t)MROWS * DCROSS * 2);
    bf16* Wqt = (bf16*)alloc((size_t)DEMBED * DEMBED * 2);
    bf16* Wkt = (bf16*)alloc((size_t)DEMBED * DCROSS * 2);
    bf16* Wvt = (bf16*)alloc((size_t)DEMBED * DCROSS * 2);
    bf16* Wot = (bf16*)alloc((size_t)DEMBED * DEMBED * 2);
    bf16* Qb  = (bf16*)alloc((size_t)MROWS * DEMBED * 2);
    bf16* Kb  = (bf16*)alloc((size_t)MROWS * DEMBED * 2);
    bf16* Vtb = (bf16*)alloc((size_t)MROWS * DEMBED * 2);  // V^T per head
    bf16* Ab  = (bf16*)alloc((size_t)MROWS * DEMBED * 2);
    if (off > ws_size) return;

    {
        PrepArgs a;
        a.wsrc[0] = Wq; a.wdst[0] = Wqt; a.wK[0] = DEMBED;
        a.wsrc[1] = Wk; a.wdst[1] = Wkt; a.wK[1] = DCROSS;
        a.wsrc[2] = Wv; a.wdst[2] = Wvt; a.wK[2] = DCROSS;
        a.wsrc[3] = Wo; a.wdst[3] = Wot; a.wK[3] = DEMBED;
        a.x = x; a.y = y; a.xb = xb; a.yb = yb;
        int ncvt = (MROWS * DEMBED / 4 + MROWS * DCROSS / 4 + 255) / 256;
        prep_all<<<NTRB + ncvt, 256, 0, stream>>>(a);
    }

    {
        QkvArgs a;
        a.xb = xb; a.yb = yb; a.Wqt = Wqt; a.Wkt = Wkt; a.Wvt = Wvt;
        a.bq = bq; a.bk = bk; a.bv = bv;
        a.Qb = Qb; a.Kb = Kb; a.Vt = Vtb;
        a.qscale = 0.125f * 1.4426950408889634f;   // 1/sqrt(64) * log2(e)
        gemm_qkv<<<768, 512, 0, stream>>>(a);
    }

    attn<<<dim3(BATCH * NHEADS, SLEN / 128), 256, 0, stream>>>(Qb, Kb, Vtb, Ab);

    gemm_o<<<dim3(MROWS / 128, DEMBED / 128), 256, 0, stream>>>(Ab, Wot, bo, out);
}

// Round 9
// 282.042 us; speedup vs baseline: 1.8925x; 1.8925x over previous
//
#include <hip/hip_runtime.h>

#define NHEADS 16
#define DEMBED 1024
#define DCROSS 768
#define DHEAD  64
#define BATCH  4
#define SLEN   2048
#define MROWS  (BATCH * SLEN)   // 8192

using bf16   = __bf16;
using bf16x8 = __attribute__((ext_vector_type(8))) __bf16;
using bf16x4 = __attribute__((ext_vector_type(4))) __bf16;
using f32x4  = __attribute__((ext_vector_type(4))) float;

__device__ __forceinline__ f32x4 mfma_bf16(bf16x8 a, bf16x8 b, f32x4 c) {
    return __builtin_amdgcn_mfma_f32_16x16x32_bf16(a, b, c, 0, 0, 0);
}

// async global->LDS, 16B per lane; lds dest = wave-uniform base + lane*16
__device__ __forceinline__ void gl2lds16(const void* g, void* l) {
    __builtin_amdgcn_global_load_lds(
        (const __attribute__((address_space(1))) void*)g,
        (__attribute__((address_space(3))) void*)l, 16, 0, 0);
}

// ---------------------------------------------------------------- prep (one kernel)
struct PrepArgs {
    const float* wsrc[4]; bf16* wdst[4]; int wK[4];
    const float *x, *y; bf16 *xb, *yb;
};
#define NTRB 4096
__global__ void prep_all(PrepArgs a) {
    const int bid = blockIdx.x;
    const int tid = threadIdx.x;
    if (bid < NTRB) {
        __shared__ float tile[32][33];
        const int which = bid >> 10, rem = bid & 1023;
        const int K = a.wK[which], N = DEMBED;
        const int n0 = (rem & 31) * 32, k0 = (rem >> 5) * 32;
        if (k0 >= K) return;
        const float* W = a.wsrc[which];
        bf16* Wt = a.wdst[which];
        const int tx = tid & 31, ty = tid >> 5;
#pragma unroll
        for (int i = 0; i < 32; i += 8)
            tile[ty + i][tx] = W[(size_t)(k0 + ty + i) * N + n0 + tx];
        __syncthreads();
#pragma unroll
        for (int i = 0; i < 32; i += 8)
            Wt[(size_t)(n0 + ty + i) * K + k0 + tx] = (bf16)tile[tx][ty + i];
    } else {
        const int n4x = MROWS * DEMBED / 4;
        const int n4y = MROWS * DCROSS / 4;
        int i = (bid - NTRB) * 256 + tid;
        const float* src; bf16* dst; int j;
        if (i < n4x) { src = a.x; dst = a.xb; j = i; }
        else { j = i - n4x; if (j >= n4y) return; src = a.y; dst = a.yb; }
        float4 v = ((const float4*)src)[j];
        bf16x4 o = { (bf16)v.x, (bf16)v.y, (bf16)v.z, (bf16)v.w };
        ((bf16x4*)dst)[j] = o;
    }
}

// ---------------------------------------------------------------- fused QKV GEMM (r6 version)
// BK=64: 128x128 tile, 256 thr, 16B async staging, XOR-swizzled LDS.
// blocks: [0,512) Q = xb@Wqt^T (*qscale), [512,1024) K = yb@Wkt^T,
// [1024,1536) V^T = Wvt@yb^T written per-head transposed.
struct QkvArgs {
    const bf16 *xb, *yb, *Wqt, *Wkt, *Wvt;
    const float *bq, *bk, *bv;
    bf16 *Qb, *Kb, *Vt;
    float qscale;
};
__global__ __launch_bounds__(256, 3) void gemm_qkv(QkvArgs a) {
    __shared__ bf16 As[128 * 64];
    __shared__ bf16 Bs[128 * 64];
    const int id = blockIdx.x;
    const int cls = id >> 9;   // 0=Q 1=K 2=V
    const bf16 *A, *Bt;
    const float* bias;
    int K, m0, n0;
    if (cls == 0) { int t = id;        m0 = (t >> 3) * 128; n0 = (t & 7) * 128;
                    A = a.xb;  Bt = a.Wqt; bias = a.bq; K = DEMBED; }
    else if (cls == 1) { int t = id - 512;  m0 = (t >> 3) * 128; n0 = (t & 7) * 128;
                    A = a.yb;  Bt = a.Wkt; bias = a.bk; K = DCROSS; }
    else { int t = id - 1024; m0 = (t >> 6) * 128; n0 = (t & 63) * 128;
                    A = a.Wvt; Bt = a.yb;  bias = a.bv; K = DCROSS; }

    const int tid  = threadIdx.x;
    const int wave = tid >> 6, lane = tid & 63;
    const int quad = lane >> 4, l15 = lane & 15;
    const int wr = wave >> 1, wc = wave & 1;

    const int srow = wave * 8 + (lane >> 3);
    const int scol = ((lane & 7) ^ (lane >> 3)) * 8;
    char* ldsA0 = (char*)As + wave * 1024;
    char* ldsB0 = (char*)Bs + wave * 1024;
    const bf16* gA0 = A + (size_t)(m0 + srow) * K + scol;
    const bf16* gB0 = Bt + (size_t)(n0 + srow) * K + scol;

    const int sw = l15 & 7;

    f32x4 acc[4][4] = {};

    for (int kt = 0; kt < K; kt += 64) {
        __syncthreads();
#pragma unroll
        for (int c = 0; c < 4; c++)
            gl2lds16(gA0 + (size_t)c * 32 * K + kt, ldsA0 + c * 4096);
#pragma unroll
        for (int c = 0; c < 4; c++)
            gl2lds16(gB0 + (size_t)c * 32 * K + kt, ldsB0 + c * 4096);
        __syncthreads();

#pragma unroll
        for (int kg = 0; kg < 2; kg++) {
            bf16x8 af[4], bfr[4];
#pragma unroll
            for (int i = 0; i < 4; i++)
                af[i] = *(const bf16x8*)((const char*)As +
                         (wr * 64 + i * 16 + l15) * 128 + (((kg * 4 + quad) ^ sw) * 16));
#pragma unroll
            for (int i = 0; i < 4; i++)
                bfr[i] = *(const bf16x8*)((const char*)Bs +
                         (wc * 64 + i * 16 + l15) * 128 + (((kg * 4 + quad) ^ sw) * 16));
#pragma unroll
            for (int fr = 0; fr < 4; fr++)
#pragma unroll
                for (int fc = 0; fc < 4; fc++)
                    acc[fr][fc] = mfma_bf16(af[fr], bfr[fc], acc[fr][fc]);
        }
    }

    if (cls < 2) {
        bf16* Cout = (cls == 0) ? a.Qb : a.Kb;
        const float alpha = (cls == 0) ? a.qscale : 1.0f;
#pragma unroll
        for (int fr = 0; fr < 4; fr++) {
            int row = m0 + wr * 64 + fr * 16 + quad * 4;
#pragma unroll
            for (int fc = 0; fc < 4; fc++) {
                int col = n0 + wc * 64 + fc * 16 + l15;
                float bv = bias[col];
#pragma unroll
                for (int r = 0; r < 4; r++)
                    Cout[(size_t)(row + r) * DEMBED + col] =
                        (bf16)((acc[fr][fc][r] + bv) * alpha);
            }
        }
    } else {
        const int b = n0 >> 11;
        const size_t bbase = (size_t)b * DEMBED * SLEN;
#pragma unroll
        for (int fr = 0; fr < 4; fr++) {
            int row = m0 + wr * 64 + fr * 16 + quad * 4;
#pragma unroll
            for (int fc = 0; fc < 4; fc++) {
                int col = n0 + wc * 64 + fc * 16 + l15;
                int s = col & (SLEN - 1);
#pragma unroll
                for (int r = 0; r < 4; r++)
                    a.Vt[bbase + (size_t)(row + r) * SLEN + s] =
                        (bf16)(acc[fr][fc][r] + bias[row + r]);
            }
        }
    }
}

// ---------------------------------------------------------------- O GEMM (BK=64)
__global__ __launch_bounds__(256, 3) void gemm_o(const bf16* __restrict__ A,
                                                 const bf16* __restrict__ Bt,
                                                 const float* __restrict__ bias,
                                                 float* __restrict__ Cout) {
    const int K = DEMBED, N = DEMBED;
    __shared__ bf16 As[128 * 64];
    __shared__ bf16 Bs[128 * 64];
    const int tid  = threadIdx.x;
    const int wave = tid >> 6, lane = tid & 63;
    const int quad = lane >> 4, l15 = lane & 15;
    const int m0 = blockIdx.x * 128, n0 = blockIdx.y * 128;
    const int wr = wave >> 1, wc = wave & 1;

    const int srow = wave * 8 + (lane >> 3);
    const int scol = ((lane & 7) ^ (lane >> 3)) * 8;
    char* ldsA0 = (char*)As + wave * 1024;
    char* ldsB0 = (char*)Bs + wave * 1024;
    const bf16* gA0 = A + (size_t)(m0 + srow) * K + scol;
    const bf16* gB0 = Bt + (size_t)(n0 + srow) * K + scol;

    const int sw = l15 & 7;

    f32x4 acc[4][4] = {};

    for (int kt = 0; kt < K; kt += 64) {
        __syncthreads();
#pragma unroll
        for (int c = 0; c < 4; c++)
            gl2lds16(gA0 + (size_t)c * 32 * K + kt, ldsA0 + c * 4096);
#pragma unroll
        for (int c = 0; c < 4; c++)
            gl2lds16(gB0 + (size_t)c * 32 * K + kt, ldsB0 + c * 4096);
        __syncthreads();

#pragma unroll
        for (int kg = 0; kg < 2; kg++) {
            bf16x8 af[4], bfr[4];
#pragma unroll
            for (int i = 0; i < 4; i++)
                af[i] = *(const bf16x8*)((const char*)As +
                         (wr * 64 + i * 16 + l15) * 128 + (((kg * 4 + quad) ^ sw) * 16));
#pragma unroll
            for (int i = 0; i < 4; i++)
                bfr[i] = *(const bf16x8*)((const char*)Bs +
                         (wc * 64 + i * 16 + l15) * 128 + (((kg * 4 + quad) ^ sw) * 16));
#pragma unroll
            for (int fr = 0; fr < 4; fr++)
#pragma unroll
                for (int fc = 0; fc < 4; fc++)
                    acc[fr][fc] = mfma_bf16(af[fr], bfr[fc], acc[fr][fc]);
        }
    }

#pragma unroll
    for (int fr = 0; fr < 4; fr++) {
        int row = m0 + wr * 64 + fr * 16 + quad * 4;
#pragma unroll
        for (int fc = 0; fc < 4; fc++) {
            int col = n0 + wc * 64 + fc * 16 + l15;
            float bv = bias[col];
#pragma unroll
            for (int r = 0; r < 4; r++)
                Cout[(size_t)(row + r) * N + col] = acc[fr][fc][r] + bv;
        }
    }
}

// ---------------------------------------------------------------- attention
// r6 structure (LDS-staged K/V via global_load_lds, 4 blocks/CU, grid (bh,qblk)
// for XCD L2 locality) + register-hoisted P fragment reads (removes 12
// redundant ds_read_b128 per wave-tile).
__global__ __launch_bounds__(256, 4) void attn(const bf16* __restrict__ Q,
                                               const bf16* __restrict__ K,
                                               const bf16* __restrict__ Vt,
                                               bf16* __restrict__ O) {
    __shared__ bf16 KsA[64 * 64];        // [key][d]   XOR-swizzled chunks
    __shared__ bf16 VsA[64 * 64];        // [d][key]   XOR-swizzled chunks
    __shared__ bf16 PsA[4 * 32 * 72];    // per-wave [q][key], pad 72

    const int tid  = threadIdx.x;
    const int wave = tid >> 6, lane = tid & 63;
    const int quad = lane >> 4, l15 = lane & 15;
    const int bh = blockIdx.x, b = bh >> 4, h = bh & 15;
    const size_t rowbase = (size_t)b * SLEN;
    const int qb = blockIdx.y * 128 + wave * 32;
    const int hc = h * DHEAD;

    bf16x8 qf[2][2];
#pragma unroll
    for (int rg = 0; rg < 2; rg++)
#pragma unroll
        for (int kg = 0; kg < 2; kg++)
            qf[rg][kg] = *(const bf16x8*)(Q + (rowbase + qb + rg * 16 + l15) * DEMBED
                                          + hc + kg * 32 + quad * 8);

    f32x4 o[2][4] = {};
    f32x4 lsv[2] = {};

    const bf16* Kbase = K + rowbase * DEMBED + hc;
    const bf16* Vbase = Vt + (size_t)bh * DHEAD * SLEN;

    const int xcol = (((tid & 7) ^ ((tid >> 3) & 7)) * 8);
    const bf16* gK = Kbase + (size_t)(tid >> 3) * DEMBED + xcol;
    const bf16* gV = Vbase + (size_t)(tid >> 3) * SLEN + xcol;
    char* ldsK = (char*)KsA + wave * 1024;
    char* ldsV = (char*)VsA + wave * 1024;
    bf16* Pw = PsA + wave * (32 * 72);

    for (int kb = 0; kb < SLEN; kb += 64) {
        __syncthreads();
        gl2lds16(gK + (size_t)kb * DEMBED, ldsK);
        gl2lds16(gK + (size_t)(kb + 32) * DEMBED, ldsK + 32 * 128);
        gl2lds16(gV + kb, ldsV);
        gl2lds16(gV + 32 * SLEN + kb, ldsV + 32 * 128);
        __syncthreads();

        f32x4 s[2][4] = {};
#pragma unroll
        for (int cg = 0; cg < 4; cg++)
#pragma unroll
            for (int kg = 0; kg < 2; kg++) {
                bf16x8 kf = *(const bf16x8*)((const char*)KsA +
                            (cg * 16 + l15) * 128 + (((kg * 4 + quad) ^ (l15 & 7)) * 16));
#pragma unroll
                for (int rg = 0; rg < 2; rg++)
                    s[rg][cg] = mfma_bf16(kf, qf[rg][kg], s[rg][cg]);
            }

#pragma unroll
        for (int rg = 0; rg < 2; rg++)
#pragma unroll
            for (int cg = 0; cg < 4; cg++) {
                f32x4 p;
                p[0] = __builtin_amdgcn_exp2f(s[rg][cg][0]);
                p[1] = __builtin_amdgcn_exp2f(s[rg][cg][1]);
                p[2] = __builtin_amdgcn_exp2f(s[rg][cg][2]);
                p[3] = __builtin_amdgcn_exp2f(s[rg][cg][3]);
                lsv[rg] += p;
                bf16x4 pb = { (bf16)p[0], (bf16)p[1], (bf16)p[2], (bf16)p[3] };
                *(bf16x4*)(Pw + (rg * 16 + l15) * 72 + cg * 16 + quad * 4) = pb;
            }

        // hoisted P fragment reads (wave-private LDS; in-wave lgkmcnt ordering)
        bf16x8 ap[2][2];
#pragma unroll
        for (int rg = 0; rg < 2; rg++)
#pragma unroll
            for (int kg = 0; kg < 2; kg++)
                ap[rg][kg] = *(const bf16x8*)(Pw + (rg * 16 + l15) * 72 + kg * 32 + quad * 8);

#pragma unroll
        for (int dg = 0; dg < 4; dg++)
#pragma unroll
            for (int kg = 0; kg < 2; kg++) {
                bf16x8 vf = *(const bf16x8*)((const char*)VsA +
                            (dg * 16 + l15) * 128 + (((kg * 4 + quad) ^ (l15 & 7)) * 16));
#pragma unroll
                for (int rg = 0; rg < 2; rg++)
                    o[rg][dg] = mfma_bf16(ap[rg][kg], vf, o[rg][dg]);
            }
    }

    float inv[2];
#pragma unroll
    for (int rg = 0; rg < 2; rg++) {
        float rs = lsv[rg][0] + lsv[rg][1] + lsv[rg][2] + lsv[rg][3];
        rs += __shfl_xor(rs, 16);
        rs += __shfl_xor(rs, 32);
        inv[rg] = 1.0f / rs;
    }
#pragma unroll
    for (int rg = 0; rg < 2; rg++)
#pragma unroll
        for (int r = 0; r < 4; r++) {
            float iv = __shfl(inv[rg], quad * 4 + r);
#pragma unroll
            for (int dg = 0; dg < 4; dg++)
                O[(rowbase + qb + rg * 16 + quad * 4 + r) * DEMBED + hc + dg * 16 + l15] =
                    (bf16)(o[rg][dg][r] * iv);
        }
}

// ---------------------------------------------------------------- launch
extern "C" void kernel_launch(void* const* d_in, const int* in_sizes, int n_in,
                              void* d_out, int out_size, void* d_ws, size_t ws_size,
                              hipStream_t stream) {
    const float* x  = (const float*)d_in[0];
    const float* y  = (const float*)d_in[1];
    const float* Wq = (const float*)d_in[2];
    const float* bq = (const float*)d_in[3];
    const float* Wk = (const float*)d_in[4];
    const float* bk = (const float*)d_in[5];
    const float* Wv = (const float*)d_in[6];
    const float* bv = (const float*)d_in[7];
    const float* Wo = (const float*)d_in[8];
    const float* bo = (const float*)d_in[9];
    float* out = (float*)d_out;

    char* ws = (char*)d_ws;
    size_t off = 0;
    auto alloc = [&](size_t bytes) {
        void* p = ws + off;
        off += (bytes + 255) & ~(size_t)255;
        return p;
    };
    bf16* xb  = (bf16*)alloc((size_t)MROWS * DEMBED * 2);
    bf16* yb  = (bf16*)alloc((size_t)MROWS * DCROSS * 2);
    bf16* Wqt = (bf16*)alloc((size_t)DEMBED * DEMBED * 2);
    bf16* Wkt = (bf16*)alloc((size_t)DEMBED * DCROSS * 2);
    bf16* Wvt = (bf16*)alloc((size_t)DEMBED * DCROSS * 2);
    bf16* Wot = (bf16*)alloc((size_t)DEMBED * DEMBED * 2);
    bf16* Qb  = (bf16*)alloc((size_t)MROWS * DEMBED * 2);
    bf16* Kb  = (bf16*)alloc((size_t)MROWS * DEMBED * 2);
    bf16* Vtb = (bf16*)alloc((size_t)MROWS * DEMBED * 2);  // V^T per head
    bf16* Ab  = (bf16*)alloc((size_t)MROWS * DEMBED * 2);
    if (off > ws_size) return;

    {
        PrepArgs a;
        a.wsrc[0] = Wq; a.wdst[0] = Wqt; a.wK[0] = DEMBED;
        a.wsrc[1] = Wk; a.wdst[1] = Wkt; a.wK[1] = DCROSS;
        a.wsrc[2] = Wv; a.wdst[2] = Wvt; a.wK[2] = DCROSS;
        a.wsrc[3] = Wo; a.wdst[3] = Wot; a.wK[3] = DEMBED;
        a.x = x; a.y = y; a.xb = xb; a.yb = yb;
        int ncvt = (MROWS * DEMBED / 4 + MROWS * DCROSS / 4 + 255) / 256;
        prep_all<<<NTRB + ncvt, 256, 0, stream>>>(a);
    }

    {
        QkvArgs a;
        a.xb = xb; a.yb = yb; a.Wqt = Wqt; a.Wkt = Wkt; a.Wvt = Wvt;
        a.bq = bq; a.bk = bk; a.bv = bv;
        a.Qb = Qb; a.Kb = Kb; a.Vt = Vtb;
        a.qscale = 0.125f * 1.4426950408889634f;   // 1/sqrt(64) * log2(e)
        gemm_qkv<<<1536, 256, 0, stream>>>(a);
    }

    attn<<<dim3(BATCH * NHEADS, SLEN / 128), 256, 0, stream>>>(Qb, Kb, Vtb, Ab);

    gemm_o<<<dim3(MROWS / 128, DEMBED / 128), 256, 0, stream>>>(Ab, Wot, bo, out);
}